// Round 15
// baseline (168.812 us; speedup 1.0000x reference)
//
#include <hip/hip_runtime.h>
#include <math.h>

typedef unsigned short ushortT;
typedef __attribute__((ext_vector_type(8))) short bf16x8;
typedef __attribute__((ext_vector_type(8))) unsigned short u16x8;
typedef __attribute__((ext_vector_type(4))) float f32x4;
typedef float f32x4u __attribute__((ext_vector_type(4), aligned(4)));

#define NN   512
#define UU   2048
#define VV   43
#define HH   512
#define KMIX 10
#define NCLS 512
#define EPSF 1e-5f
#define KCAT 555     // H + V
#define PLANE 262144 // 512*512

// d_out offsets (floats)
#define OFF_DIST  0
#define OFF_H2    262144
#define OFF_H3    524288
#define OFF_PHI   786432
#define OFF_WT    1835008
#define OFF_KAPPA 1857024

__device__ __forceinline__ ushortT f2bf(float f) {
    unsigned int u = __builtin_bit_cast(unsigned int, f);
    u = (u + 0x7fffu + ((u >> 16) & 1u)) >> 16;
    return (ushortT)u;
}

__device__ __forceinline__ u16x8 cv8(float4 lo, float4 hi) {
    u16x8 o;
    o[0]=f2bf(lo.x); o[1]=f2bf(lo.y); o[2]=f2bf(lo.z); o[3]=f2bf(lo.w);
    o[4]=f2bf(hi.x); o[5]=f2bf(hi.y); o[6]=f2bf(hi.z); o[7]=f2bf(hi.w);
    return o;
}

struct AttnS {
    float x[KCAT];
    float sm[32];
    float aL[KMIX], bL[KMIX], kL[KMIX], um[KMIX];
    float red[4*VV];
    float wtv[VV+1];
};

#define MFMA16(a,b,c) __builtin_amdgcn_mfma_f32_16x16x32_bf16(a,b,c,0,0,0)

// ---------------------------------------------------------------------------
// Gate-grouped MFMA GEMM body (R11/R13-verbatim).
// MODE 0: epilogue per EPI (0=bias store). MODE 1: store aR/aZ/aN2 -> preC
// planes (gh precompute). MODE 2: combine preC planes + GRU epilogue (EPI 1/2).
template<int NG, int NSA, int NSB, int EPI, int WIK, int MODE>
__device__ __forceinline__ void gemm_body(
    int bj0, int bm0, ushortT* lds0, ushortT* lds1,
    const ushortT* __restrict__ Ai, const float* __restrict__ Wi,
    const float* __restrict__ Ah, const float* __restrict__ Wh,
    const float* __restrict__ bih, const float* __restrict__ bhh,
    const float* __restrict__ hprev, const float* __restrict__ resv,
    float* __restrict__ outF, ushortT* __restrict__ outB,
    const float* __restrict__ Yb, float* __restrict__ preC)
{
    constexpr int NS = NSA + NSB;
    int tid = threadIdx.x, lane = tid & 63, wid = tid >> 6;
    int wm = wid >> 1, wj = wid & 1;
    int fcol = lane & 15, g2 = lane >> 4;
    int arow = tid >> 3, aslot = tid & 7;

    float4 stgA[NG+1][2], stgB[NG+1][2];
    const float4 fz = {0.f, 0.f, 0.f, 0.f};

    auto loadregs = [&](int s, float4 (&dst)[NG+1][2]) {
        if (s < NSA) {
            dst[0][0] = *(const float4*)(Ai + (size_t)(bm0 + arow)*(NSA*64) + s*64 + aslot*8);
#pragma unroll
            for (int q = 1; q <= NG; ++q) {
                int unit = (q-1)*256 + tid;
                int brow = unit >> 3, bslot = unit & 7;
                int gate = brow >> 5, r = brow & 31;
                int col = s*64 + bslot*8;
                const float* src = Wi + (size_t)(gate*512 + bj0 + r)*WIK + col;
                if constexpr (WIK % 64 != 0) {
                    dst[q][0] = (col + 4 <= WIK) ? *(const float4*)src : fz;
                    dst[q][1] = (col + 8 <= WIK) ? *(const float4*)(src + 4) : fz;
                } else {
                    dst[q][0] = *(const float4*)src;
                    dst[q][1] = *(const float4*)(src + 4);
                }
            }
        } else {
            int kb = (s - NSA)*64;
            const float* srcA = Ah + (size_t)(bm0 + arow)*512 + kb + aslot*8;
            dst[0][0] = *(const float4*)srcA;
            dst[0][1] = *(const float4*)(srcA + 4);
#pragma unroll
            for (int q = 1; q <= NG; ++q) {
                int unit = (q-1)*256 + tid;
                int brow = unit >> 3, bslot = unit & 7;
                int gate = brow >> 5, r = brow & 31;
                const float* src = Wh + (size_t)(gate*512 + bj0 + r)*512 + kb + bslot*8;
                dst[q][0] = *(const float4*)src;
                dst[q][1] = *(const float4*)(src + 4);
            }
        }
    };
    auto stow = [&](int s, const float4 (&src)[NG+1][2], ushortT* buf) {
        if (s < NSA) {
            *(float4*)(buf + arow*64 + (aslot ^ (arow & 7))*8) = src[0][0];
        } else {
            *(u16x8*)(buf + arow*64 + (aslot ^ (arow & 7))*8) = cv8(src[0][0], src[0][1]);
        }
#pragma unroll
        for (int q = 1; q <= NG; ++q) {
            int unit = (q-1)*256 + tid;
            int brow = unit >> 3, bslot = unit & 7;
            *(u16x8*)(buf + 2048 + brow*64 + (bslot ^ (brow & 7))*8) = cv8(src[q][0], src[q][1]);
        }
    };

    f32x4 aR = {0.f,0.f,0.f,0.f}, aZ = {0.f,0.f,0.f,0.f};
    f32x4 aN1 = {0.f,0.f,0.f,0.f}, aN2 = {0.f,0.f,0.f,0.f};

    int ra = wm*16 + fcol, rb = wj*16 + fcol;

    loadregs(0, stgA);
    stow(0, stgA, lds0);
    if (NS > 1) loadregs(1, stgB);
    __syncthreads();

#pragma unroll
    for (int s = 0; s < NS; ++s) {
        ushortT* cur = (s & 1) ? lds1 : lds0;
        ushortT* nxt = (s & 1) ? lds0 : lds1;
        if (s + 2 < NS) {
            if (s & 1) loadregs(s + 2, stgB); else loadregs(s + 2, stgA);
        }
        bf16x8 af0 = *(const bf16x8*)(cur + ra*64 + ((g2    ) ^ (ra & 7))*8);
        bf16x8 af1 = *(const bf16x8*)(cur + ra*64 + ((4 + g2) ^ (ra & 7))*8);
        bf16x8 b0[NG], b1[NG];
#pragma unroll
        for (int g = 0; g < NG; ++g) {
            int rbt = g*32 + rb;
            b0[g] = *(const bf16x8*)(cur + 2048 + rbt*64 + ((g2    ) ^ (rbt & 7))*8);
            b1[g] = *(const bf16x8*)(cur + 2048 + rbt*64 + ((4 + g2) ^ (rbt & 7))*8);
        }
        if (s + 1 < NS) {
            if (s & 1) stow(s + 1, stgA, nxt); else stow(s + 1, stgB, nxt);
        }
        aR = MFMA16(af0, b0[0], aR);
        aR = MFMA16(af1, b1[0], aR);
        if constexpr (NG >= 2) {
            aZ = MFMA16(af0, b0[1], aZ);
            aZ = MFMA16(af1, b1[1], aZ);
        }
        if constexpr (NG >= 3) {
            if (s < NSA) {
                aN1 = MFMA16(af0, b0[2], aN1);
                aN1 = MFMA16(af1, b1[2], aN1);
            } else {
                aN2 = MFMA16(af0, b0[2], aN2);
                aN2 = MFMA16(af1, b1[2], aN2);
            }
        }
        __syncthreads();
    }

    int row0 = bm0 + wm*16 + (lane >> 4)*4;
    int col  = bj0 + wj*16 + fcol;

    if constexpr (MODE == 1) {
#pragma unroll
        for (int e = 0; e < 4; ++e) {
            size_t off = (size_t)(row0 + e)*512 + col;
            preC[off]           = aR[e];
            preC[PLANE + off]   = aZ[e];
            preC[2*PLANE + off] = aN2[e];
        }
    } else if constexpr (EPI == 0) {
        float b = Yb[col];
#pragma unroll
        for (int e = 0; e < 4; ++e)
            outF[(size_t)(row0 + e)*512 + col] = aR[e] + b;
    } else {
        float b_r  = bih[col] + bhh[col];
        float b_z  = bih[512 + col] + bhh[512 + col];
        float b_ni = bih[1024 + col];
        float b_nh = bhh[1024 + col];
#pragma unroll
        for (int e = 0; e < 4; ++e) {
            size_t off = (size_t)(row0 + e)*512 + col;
            float gr = aR[e], gz = aZ[e], gnh = aN2[e];
            if constexpr (MODE == 2) {
                gr  += preC[off];
                gz  += preC[PLANE + off];
                gnh  = preC[2*PLANE + off];
            }
            float r  = 1.f/(1.f + __expf(-(gr + b_r)));
            float z  = 1.f/(1.f + __expf(-(gz + b_z)));
            float nn = tanhf(aN1[e] + b_ni + r*(gnh + b_nh));
            float h  = (1.f - z)*nn + z*hprev[off];
            outF[off] = h;
            float xo = (EPI == 2) ? (h + resv[off]) : h;
            outB[off] = f2bf(fmaxf(xo, 0.f));
        }
    }
}

// ---------------------------------------------------------------------------
// Launch 1: attn (blocks 0..511) + gh2 (512..767) + gh3 (768..1023).
// Block 0 also zeroes the producer-consumer flags for launch 2 (ws is not
// re-poisoned between replays; launch boundary publishes the zeros).
__global__ __launch_bounds__(256) void attn_gh(
    const float* __restrict__ xt, const float* __restrict__ cx,
    const float* __restrict__ eh, const float* __restrict__ wt_1,
    const float* __restrict__ Ww, const float* __restrict__ Wb,
    const float* __restrict__ kappa_prev,
    float* __restrict__ phi_out, float* __restrict__ wt_out,
    float* __restrict__ kappa_out, ushortT* __restrict__ A2,
    const float* __restrict__ h2p, const float* __restrict__ w2hh,
    const float* __restrict__ h3p, const float* __restrict__ w3hh,
    float* __restrict__ gh2C, float* __restrict__ gh3C,
    unsigned* __restrict__ flags)
{
    __shared__ __align__(16) ushortT smem[2][4*32*64];   // 32 KB
    int bb = blockIdx.x, t = threadIdx.x;

    if (bb == 0 && t < 32) flags[t] = 0u;

    if (bb >= NN) {
        int gb = bb - NN;
        int sub = gb & 255;
        int bj0 = (sub & 15)*32, bm0 = (sub >> 4)*32;
        if (gb < 256)
            gemm_body<3, 0, 8, 1, 512, 1>(bj0, bm0, &smem[0][0], &smem[1][0],
                nullptr, nullptr, h2p, w2hh, nullptr, nullptr, nullptr, nullptr,
                nullptr, nullptr, nullptr, gh2C);
        else
            gemm_body<3, 0, 8, 1, 512, 1>(bj0, bm0, &smem[0][0], &smem[1][0],
                nullptr, nullptr, h3p, w3hh, nullptr, nullptr, nullptr, nullptr,
                nullptr, nullptr, nullptr, gh3C);
        return;
    }

    // ---------------- attn path ----------------
    AttnS* S = (AttnS*)&smem[0][0];
    int n = bb;
    int lane = t & 63, wid = t >> 6;
    const float* cxn = cx + (size_t)n*UU*VV;

    const float* rowp0 = cxn + (size_t)t*VV;
    f32x4u r0[10]; f32x4u rt0;
#pragma unroll
    for (int q = 0; q < 10; ++q) r0[q] = *(const f32x4u*)(rowp0 + q*4);
    rt0 = *(const f32x4u*)(rowp0 + 39);

    for (int i = t; i < KCAT; i += 256)
        S->x[i] = (i < HH) ? eh[(size_t)n*HH + i] : wt_1[n*VV + (i - HH)];
    __syncthreads();
#pragma unroll
    for (int rr = 0; rr < 8; ++rr) {
        int g = rr*4 + wid;
        float v = 0.f;
        if (g < 30) {
            const float* w = Ww + (size_t)g*KCAT;
#pragma unroll
            for (int q = 0; q < 9; ++q) {
                int i = q*64 + lane;
                if (i < KCAT) v += S->x[i]*w[i];
            }
        }
        v += __shfl_xor(v, 32, 64); v += __shfl_xor(v, 16, 64); v += __shfl_xor(v, 8, 64);
        v += __shfl_xor(v, 4, 64);  v += __shfl_xor(v, 2, 64);  v += __shfl_xor(v, 1, 64);
        if (lane == 0 && g < 30) S->sm[g] = v;
    }
    __syncthreads();
    if (t < 30) {
        float ev = __expf(S->sm[t] + Wb[t]);
        if (t < 10)       S->aL[t] = ev + EPSF;
        else if (t < 20)  S->bL[t-10] = ev + EPSF;
        else { float kap = kappa_prev[n*KMIX + (t-20)] + ev; S->kL[t-20] = kap;
               kappa_out[n*KMIX + (t-20)] = kap; }
    }
    __syncthreads();
    if (t < KMIX)
        S->um[t] = S->kL[t] + sqrtf(fmaxf(60.f + __logf(S->aL[t]), 0.f) / S->bL[t]);
    __syncthreads();
    float ulim = S->um[0];
#pragma unroll
    for (int k = 1; k < KMIX; ++k) ulim = fmaxf(ulim, S->um[k]);
    int nchunks = min(8, (int)(ulim) / 256 + 1);
    nchunks = __builtin_amdgcn_readfirstlane(nchunks);

    float aL[KMIX], bL[KMIX], kL[KMIX];
#pragma unroll
    for (int k = 0; k < KMIX; ++k) { aL[k] = S->aL[k]; bL[k] = S->bL[k]; kL[k] = S->kL[k]; }

    // phi: support-truncated (wave-uniform); beyond ulim reference < e^-60
    float phi_reg[8];
#pragma unroll
    for (int c = 0; c < 8; ++c) {
        float s = 0.f;
        if ((float)(c*256 + wid*64) <= ulim) {
            int u = c*256 + t; float uu = (float)u;
#pragma unroll
            for (int k = 0; k < KMIX; ++k) { float d = kL[k] - uu; s += aL[k]*__expf(-bL[k]*d*d); }
        }
        phi_reg[c] = s;
        phi_out[(size_t)n*UU + c*256 + t] = s;
    }

    float acc[VV];
    {
        float p = phi_reg[0];
#pragma unroll
        for (int q = 0; q < 10; ++q) {
            acc[q*4+0] = r0[q].x*p; acc[q*4+1] = r0[q].y*p;
            acc[q*4+2] = r0[q].z*p; acc[q*4+3] = r0[q].w*p;
        }
        acc[40] = rt0.y*p; acc[41] = rt0.z*p; acc[42] = rt0.w*p;
    }
#pragma unroll
    for (int c = 1; c < 8; ++c) {
        if (c < nchunks) {
            const float* rowp = cxn + (size_t)(c*256 + t)*VV;
            f32x4u r[10];
#pragma unroll
            for (int q = 0; q < 10; ++q) r[q] = *(const f32x4u*)(rowp + q*4);
            f32x4u rt = *(const f32x4u*)(rowp + 39);
            float p = phi_reg[c];
#pragma unroll
            for (int q = 0; q < 10; ++q) {
                acc[q*4+0] += r[q].x*p; acc[q*4+1] += r[q].y*p;
                acc[q*4+2] += r[q].z*p; acc[q*4+3] += r[q].w*p;
            }
            acc[40] += rt.y*p; acc[41] += rt.z*p; acc[42] += rt.w*p;
        }
    }

#pragma unroll
    for (int v = 0; v < VV; ++v) {
        float val = acc[v];
#pragma unroll
        for (int off = 32; off > 0; off >>= 1) val += __shfl_down(val, off, 64);
        if (lane == 0) S->red[wid*VV + v] = val;
    }
    __syncthreads();
    if (t < VV) {
        float w4 = S->red[t] + S->red[VV+t] + S->red[2*VV+t] + S->red[3*VV+t];
        wt_out[n*VV + t] = w4; S->wtv[t] = w4;
    }
    __syncthreads();
    if (t < 64) {
        float v = (t == 0) ? xt[n] : (t < 44 ? S->wtv[t-1] : 0.f);
        A2[(size_t)n*64 + t] = f2bf(v);
    }
}

// ---------------------------------------------------------------------------
// Launch 2: fused GRU2-finish | GRU3-finish | dist with per-bm flag handoff.
// Blocks 0..255: GRU2 (producer of h2o/A3i, flagA[bm]).
// Blocks 256..511: spin flagA[bm]==16, GRU3 (producer of h3o/Ad, flagB[bm]).
// Blocks 512..767: spin flagB[bm]==16, dist.
// 768 blocks x 32KB LDS = 3/CU -> all co-resident; no dispatch-order deadlock.
__global__ __launch_bounds__(256) void tail_kernel(
    const ushortT* __restrict__ A2, const float* __restrict__ w2ih,
    const float* __restrict__ gh2C, const float* __restrict__ b2ih,
    const float* __restrict__ b2hh, const float* __restrict__ h2p,
    const float* __restrict__ w3ih, const float* __restrict__ gh3C,
    const float* __restrict__ b3ih, const float* __restrict__ b3hh,
    const float* __restrict__ h3p, const float* __restrict__ Yw,
    const float* __restrict__ Yb,
    float* __restrict__ h2o, float* __restrict__ h3o,
    ushortT* __restrict__ A3i, ushortT* __restrict__ Ad,
    float* __restrict__ dist, unsigned* __restrict__ flagA,
    unsigned* __restrict__ flagB)
{
    __shared__ __align__(16) ushortT lds0[4*32*64];
    __shared__ __align__(16) ushortT lds1[4*32*64];
    int bb = blockIdx.x, tid = threadIdx.x;
    int sub = bb & 255;
    int bj0 = (sub & 15)*32, bm0 = (sub >> 4)*32;
    int bmIdx = sub >> 4;

    if (bb < 256) {
        gemm_body<3, 1, 0, 1, 44, 2>(bj0, bm0, lds0, lds1,
            A2, w2ih, nullptr, nullptr, b2ih, b2hh, h2p, nullptr,
            h2o, A3i, nullptr, const_cast<float*>(gh2C));
        __syncthreads();
        if (tid == 0) {
            __threadfence();
            __hip_atomic_fetch_add(flagA + bmIdx, 1u, __ATOMIC_RELEASE, __HIP_MEMORY_SCOPE_AGENT);
        }
    } else if (bb < 512) {
        if (tid == 0) {
            while (__hip_atomic_load(flagA + bmIdx, __ATOMIC_ACQUIRE, __HIP_MEMORY_SCOPE_AGENT) < 16u)
                __builtin_amdgcn_s_sleep(8);
            __threadfence();
        }
        __syncthreads();
        gemm_body<3, 8, 0, 2, 512, 2>(bj0, bm0, lds0, lds1,
            A3i, w3ih, nullptr, nullptr, b3ih, b3hh, h3p, h2o,
            h3o, Ad, nullptr, const_cast<float*>(gh3C));
        __syncthreads();
        if (tid == 0) {
            __threadfence();
            __hip_atomic_fetch_add(flagB + bmIdx, 1u, __ATOMIC_RELEASE, __HIP_MEMORY_SCOPE_AGENT);
        }
    } else {
        if (tid == 0) {
            while (__hip_atomic_load(flagB + bmIdx, __ATOMIC_ACQUIRE, __HIP_MEMORY_SCOPE_AGENT) < 16u)
                __builtin_amdgcn_s_sleep(8);
            __threadfence();
        }
        __syncthreads();
        gemm_body<1, 8, 0, 0, 512, 0>(bj0, bm0, lds0, lds1,
            Ad, Yw, nullptr, nullptr, nullptr, nullptr, nullptr, nullptr,
            dist, nullptr, Yb, nullptr);
    }
}

// ---------------------------------------------------------------------------
extern "C" void kernel_launch(void* const* d_in, const int* in_sizes, int n_in,
                              void* d_out, int out_size, void* d_ws, size_t ws_size,
                              hipStream_t stream)
{
    const float* xt   = (const float*)d_in[0];
    const float* cx   = (const float*)d_in[1];
    const float* eh   = (const float*)d_in[2];
    const float* wt_1 = (const float*)d_in[3];
    const float* h2p  = (const float*)d_in[4];
    const float* h3p  = (const float*)d_in[5];
    const float* kp   = (const float*)d_in[6];
    const float* Ww   = (const float*)d_in[7];
    const float* Wb   = (const float*)d_in[8];
    const float* w2ih = (const float*)d_in[9];
    const float* w2hh = (const float*)d_in[10];
    const float* b2ih = (const float*)d_in[11];
    const float* b2hh = (const float*)d_in[12];
    const float* w3ih = (const float*)d_in[13];
    const float* w3hh = (const float*)d_in[14];
    const float* b3ih = (const float*)d_in[15];
    const float* b3hh = (const float*)d_in[16];
    const float* Yw   = (const float*)d_in[17];
    const float* Yb   = (const float*)d_in[18];

    float* out = (float*)d_out;
    float* dist = out + OFF_DIST;
    float* h2o  = out + OFF_H2;
    float* h3o  = out + OFF_H3;
    float* phi  = out + OFF_PHI;
    float* wto  = out + OFF_WT;
    float* kapo = out + OFF_KAPPA;

    char* p = (char*)d_ws;
    ushortT* A2   = (ushortT*)p;  p += (size_t)512*64*2;
    ushortT* A3i  = (ushortT*)p;  p += (size_t)512*512*2;
    ushortT* Ad   = (ushortT*)p;  p += (size_t)512*512*2;
    float*   gh2C = (float*)p;    p += (size_t)3*PLANE*4;
    float*   gh3C = (float*)p;    p += (size_t)3*PLANE*4;
    unsigned* flags = (unsigned*)p;  p += 128;   // flagA[16] | flagB[16]

    // L1: attn + gh2 + gh3 (input-only deps); block 0 zeroes flags
    attn_gh<<<1024, 256, 0, stream>>>(
        xt, cx, eh, wt_1, Ww, Wb, kp, phi, wto, kapo, A2,
        h2p, w2hh, h3p, w3hh, gh2C, gh3C, flags);
    // L2: fused GRU2|GRU3|dist with per-bm producer-consumer flags
    tail_kernel<<<768, 256, 0, stream>>>(
        A2, w2ih, gh2C, b2ih, b2hh, h2p,
        w3ih, gh3C, b3ih, b3hh, h3p, Yw, Yb,
        h2o, h3o, A3i, Ad, dist, flags, flags + 16);
}

// Round 16
// 49.935 us; speedup vs baseline: 3.3806x; 3.3806x over previous
//
#include <hip/hip_runtime.h>
#include <math.h>

typedef unsigned short ushortT;
typedef __attribute__((ext_vector_type(8))) short bf16x8;
typedef __attribute__((ext_vector_type(8))) unsigned short u16x8;
typedef __attribute__((ext_vector_type(4))) float f32x4;
typedef float f32x4u __attribute__((ext_vector_type(4), aligned(4)));

#define NN   512
#define UU   2048
#define VV   43
#define HH   512
#define KMIX 10
#define NCLS 512
#define EPSF 1e-5f
#define KCAT 555     // H + V
#define PLANE 262144 // 512*512

// d_out offsets (floats)
#define OFF_DIST  0
#define OFF_H2    262144
#define OFF_H3    524288
#define OFF_PHI   786432
#define OFF_WT    1835008
#define OFF_KAPPA 1857024

__device__ __forceinline__ ushortT f2bf(float f) {
    unsigned int u = __builtin_bit_cast(unsigned int, f);
    u = (u + 0x7fffu + ((u >> 16) & 1u)) >> 16;
    return (ushortT)u;
}

__device__ __forceinline__ u16x8 cv8(float4 lo, float4 hi) {
    u16x8 o;
    o[0]=f2bf(lo.x); o[1]=f2bf(lo.y); o[2]=f2bf(lo.z); o[3]=f2bf(lo.w);
    o[4]=f2bf(hi.x); o[5]=f2bf(hi.y); o[6]=f2bf(hi.z); o[7]=f2bf(hi.w);
    return o;
}

struct AttnS {
    float x[KCAT];
    float sm[32];
    float aL[KMIX], bL[KMIX], kL[KMIX], um[KMIX];
    float red[4*VV];
    float wtv[VV+1];
};

#define MFMA16(a,b,c) __builtin_amdgcn_mfma_f32_16x16x32_bf16(a,b,c,0,0,0)

// ---------------------------------------------------------------------------
// Gate-grouped MFMA GEMM body.
// MODE 0: epilogue per EPI (0=bias store). MODE 1: store aR/aZ/aN2 -> preC
// planes (gh precompute). MODE 2: combine preC planes + GRU epilogue (EPI 1/2).
template<int NG, int NSA, int NSB, int EPI, int WIK, int MODE>
__device__ __forceinline__ void gemm_body(
    int bj0, int bm0, ushortT* lds0, ushortT* lds1,
    const ushortT* __restrict__ Ai, const float* __restrict__ Wi,
    const float* __restrict__ Ah, const float* __restrict__ Wh,
    const float* __restrict__ bih, const float* __restrict__ bhh,
    const float* __restrict__ hprev, const float* __restrict__ resv,
    float* __restrict__ outF, ushortT* __restrict__ outB,
    const float* __restrict__ Yb, float* __restrict__ preC)
{
    constexpr int NS = NSA + NSB;
    int tid = threadIdx.x, lane = tid & 63, wid = tid >> 6;
    int wm = wid >> 1, wj = wid & 1;
    int fcol = lane & 15, g2 = lane >> 4;
    int arow = tid >> 3, aslot = tid & 7;

    float4 stgA[NG+1][2], stgB[NG+1][2];
    const float4 fz = {0.f, 0.f, 0.f, 0.f};

    auto loadregs = [&](int s, float4 (&dst)[NG+1][2]) {
        if (s < NSA) {
            dst[0][0] = *(const float4*)(Ai + (size_t)(bm0 + arow)*(NSA*64) + s*64 + aslot*8);
#pragma unroll
            for (int q = 1; q <= NG; ++q) {
                int unit = (q-1)*256 + tid;
                int brow = unit >> 3, bslot = unit & 7;
                int gate = brow >> 5, r = brow & 31;
                int col = s*64 + bslot*8;
                const float* src = Wi + (size_t)(gate*512 + bj0 + r)*WIK + col;
                if constexpr (WIK % 64 != 0) {
                    dst[q][0] = (col + 4 <= WIK) ? *(const float4*)src : fz;
                    dst[q][1] = (col + 8 <= WIK) ? *(const float4*)(src + 4) : fz;
                } else {
                    dst[q][0] = *(const float4*)src;
                    dst[q][1] = *(const float4*)(src + 4);
                }
            }
        } else {
            int kb = (s - NSA)*64;
            const float* srcA = Ah + (size_t)(bm0 + arow)*512 + kb + aslot*8;
            dst[0][0] = *(const float4*)srcA;
            dst[0][1] = *(const float4*)(srcA + 4);
#pragma unroll
            for (int q = 1; q <= NG; ++q) {
                int unit = (q-1)*256 + tid;
                int brow = unit >> 3, bslot = unit & 7;
                int gate = brow >> 5, r = brow & 31;
                const float* src = Wh + (size_t)(gate*512 + bj0 + r)*512 + kb + bslot*8;
                dst[q][0] = *(const float4*)src;
                dst[q][1] = *(const float4*)(src + 4);
            }
        }
    };
    auto stow = [&](int s, const float4 (&src)[NG+1][2], ushortT* buf) {
        if (s < NSA) {
            *(float4*)(buf + arow*64 + (aslot ^ (arow & 7))*8) = src[0][0];
        } else {
            *(u16x8*)(buf + arow*64 + (aslot ^ (arow & 7))*8) = cv8(src[0][0], src[0][1]);
        }
#pragma unroll
        for (int q = 1; q <= NG; ++q) {
            int unit = (q-1)*256 + tid;
            int brow = unit >> 3, bslot = unit & 7;
            *(u16x8*)(buf + 2048 + brow*64 + (bslot ^ (brow & 7))*8) = cv8(src[q][0], src[q][1]);
        }
    };

    f32x4 aR = {0.f,0.f,0.f,0.f}, aZ = {0.f,0.f,0.f,0.f};
    f32x4 aN1 = {0.f,0.f,0.f,0.f}, aN2 = {0.f,0.f,0.f,0.f};

    int ra = wm*16 + fcol, rb = wj*16 + fcol;

    loadregs(0, stgA);
    stow(0, stgA, lds0);
    if (NS > 1) loadregs(1, stgB);
    __syncthreads();

#pragma unroll
    for (int s = 0; s < NS; ++s) {
        ushortT* cur = (s & 1) ? lds1 : lds0;
        ushortT* nxt = (s & 1) ? lds0 : lds1;
        if (s + 2 < NS) {
            if (s & 1) loadregs(s + 2, stgB); else loadregs(s + 2, stgA);
        }
        bf16x8 af0 = *(const bf16x8*)(cur + ra*64 + ((g2    ) ^ (ra & 7))*8);
        bf16x8 af1 = *(const bf16x8*)(cur + ra*64 + ((4 + g2) ^ (ra & 7))*8);
        bf16x8 b0[NG], b1[NG];
#pragma unroll
        for (int g = 0; g < NG; ++g) {
            int rbt = g*32 + rb;
            b0[g] = *(const bf16x8*)(cur + 2048 + rbt*64 + ((g2    ) ^ (rbt & 7))*8);
            b1[g] = *(const bf16x8*)(cur + 2048 + rbt*64 + ((4 + g2) ^ (rbt & 7))*8);
        }
        if (s + 1 < NS) {
            if (s & 1) stow(s + 1, stgA, nxt); else stow(s + 1, stgB, nxt);
        }
        aR = MFMA16(af0, b0[0], aR);
        aR = MFMA16(af1, b1[0], aR);
        if constexpr (NG >= 2) {
            aZ = MFMA16(af0, b0[1], aZ);
            aZ = MFMA16(af1, b1[1], aZ);
        }
        if constexpr (NG >= 3) {
            if (s < NSA) {
                aN1 = MFMA16(af0, b0[2], aN1);
                aN1 = MFMA16(af1, b1[2], aN1);
            } else {
                aN2 = MFMA16(af0, b0[2], aN2);
                aN2 = MFMA16(af1, b1[2], aN2);
            }
        }
        __syncthreads();
    }

    int row0 = bm0 + wm*16 + (lane >> 4)*4;
    int col  = bj0 + wj*16 + fcol;

    if constexpr (MODE == 1) {
#pragma unroll
        for (int e = 0; e < 4; ++e) {
            size_t off = (size_t)(row0 + e)*512 + col;
            preC[off]           = aR[e];
            preC[PLANE + off]   = aZ[e];
            preC[2*PLANE + off] = aN2[e];
        }
    } else if constexpr (EPI == 0) {
        float b = Yb[col];
#pragma unroll
        for (int e = 0; e < 4; ++e)
            outF[(size_t)(row0 + e)*512 + col] = aR[e] + b;
    } else {
        float b_r  = bih[col] + bhh[col];
        float b_z  = bih[512 + col] + bhh[512 + col];
        float b_ni = bih[1024 + col];
        float b_nh = bhh[1024 + col];
#pragma unroll
        for (int e = 0; e < 4; ++e) {
            size_t off = (size_t)(row0 + e)*512 + col;
            float gr = aR[e], gz = aZ[e], gnh = aN2[e];
            if constexpr (MODE == 2) {
                gr  += preC[off];
                gz  += preC[PLANE + off];
                gnh  = preC[2*PLANE + off];
            }
            float r  = 1.f/(1.f + __expf(-(gr + b_r)));
            float z  = 1.f/(1.f + __expf(-(gz + b_z)));
            float nn = tanhf(aN1[e] + b_ni + r*(gnh + b_nh));
            float h  = (1.f - z)*nn + z*hprev[off];
            outF[off] = h;
            float xo = (EPI == 2) ? (h + resv[off]) : h;
            outB[off] = f2bf(fmaxf(xo, 0.f));
        }
    }
}

// ---------------------------------------------------------------------------
// Launch 1: attn (blocks 0..511) + gh2 (512..767) + gh3 (768..1023).
// gh GEMMs depend only on kernel inputs -> co-resident with latency-bound attn.
__global__ __launch_bounds__(256) void attn_gh(
    const float* __restrict__ xt, const float* __restrict__ cx,
    const float* __restrict__ eh, const float* __restrict__ wt_1,
    const float* __restrict__ Ww, const float* __restrict__ Wb,
    const float* __restrict__ kappa_prev,
    float* __restrict__ phi_out, float* __restrict__ wt_out,
    float* __restrict__ kappa_out, ushortT* __restrict__ A2,
    const float* __restrict__ h2p, const float* __restrict__ w2hh,
    const float* __restrict__ h3p, const float* __restrict__ w3hh,
    float* __restrict__ gh2C, float* __restrict__ gh3C)
{
    __shared__ __align__(16) ushortT smem[2][4*32*64];   // 32 KB
    int bb = blockIdx.x, t = threadIdx.x;

    if (bb >= NN) {
        int gb = bb - NN;
        int sub = gb & 255;
        int bj0 = (sub & 15)*32, bm0 = (sub >> 4)*32;
        if (gb < 256)
            gemm_body<3, 0, 8, 1, 512, 1>(bj0, bm0, &smem[0][0], &smem[1][0],
                nullptr, nullptr, h2p, w2hh, nullptr, nullptr, nullptr, nullptr,
                nullptr, nullptr, nullptr, gh2C);
        else
            gemm_body<3, 0, 8, 1, 512, 1>(bj0, bm0, &smem[0][0], &smem[1][0],
                nullptr, nullptr, h3p, w3hh, nullptr, nullptr, nullptr, nullptr,
                nullptr, nullptr, nullptr, gh3C);
        return;
    }

    // ---------------- attn path ----------------
    AttnS* S = (AttnS*)&smem[0][0];
    int n = bb;
    int lane = t & 63, wid = t >> 6;
    const float* cxn = cx + (size_t)n*UU*VV;

    const float* rowp0 = cxn + (size_t)t*VV;
    f32x4u r0[10]; f32x4u rt0;
#pragma unroll
    for (int q = 0; q < 10; ++q) r0[q] = *(const f32x4u*)(rowp0 + q*4);
    rt0 = *(const f32x4u*)(rowp0 + 39);

    for (int i = t; i < KCAT; i += 256)
        S->x[i] = (i < HH) ? eh[(size_t)n*HH + i] : wt_1[n*VV + (i - HH)];
    __syncthreads();
#pragma unroll
    for (int rr = 0; rr < 8; ++rr) {
        int g = rr*4 + wid;
        float v = 0.f;
        if (g < 30) {
            const float* w = Ww + (size_t)g*KCAT;
#pragma unroll
            for (int q = 0; q < 9; ++q) {
                int i = q*64 + lane;
                if (i < KCAT) v += S->x[i]*w[i];
            }
        }
        v += __shfl_xor(v, 32, 64); v += __shfl_xor(v, 16, 64); v += __shfl_xor(v, 8, 64);
        v += __shfl_xor(v, 4, 64);  v += __shfl_xor(v, 2, 64);  v += __shfl_xor(v, 1, 64);
        if (lane == 0 && g < 30) S->sm[g] = v;
    }
    __syncthreads();
    if (t < 30) {
        float ev = __expf(S->sm[t] + Wb[t]);
        if (t < 10)       S->aL[t] = ev + EPSF;
        else if (t < 20)  S->bL[t-10] = ev + EPSF;
        else { float kap = kappa_prev[n*KMIX + (t-20)] + ev; S->kL[t-20] = kap;
               kappa_out[n*KMIX + (t-20)] = kap; }
    }
    __syncthreads();
    if (t < KMIX)
        S->um[t] = S->kL[t] + sqrtf(fmaxf(60.f + __logf(S->aL[t]), 0.f) / S->bL[t]);
    __syncthreads();
    float ulim = S->um[0];
#pragma unroll
    for (int k = 1; k < KMIX; ++k) ulim = fmaxf(ulim, S->um[k]);
    int nchunks = min(8, (int)(ulim) / 256 + 1);
    nchunks = __builtin_amdgcn_readfirstlane(nchunks);

    float aL[KMIX], bL[KMIX], kL[KMIX];
#pragma unroll
    for (int k = 0; k < KMIX; ++k) { aL[k] = S->aL[k]; bL[k] = S->bL[k]; kL[k] = S->kL[k]; }

    // phi: support-truncated (wave-uniform); beyond ulim reference < e^-60
    float phi_reg[8];
#pragma unroll
    for (int c = 0; c < 8; ++c) {
        float s = 0.f;
        if ((float)(c*256 + wid*64) <= ulim) {
            int u = c*256 + t; float uu = (float)u;
#pragma unroll
            for (int k = 0; k < KMIX; ++k) { float d = kL[k] - uu; s += aL[k]*__expf(-bL[k]*d*d); }
        }
        phi_reg[c] = s;
        phi_out[(size_t)n*UU + c*256 + t] = s;
    }

    float acc[VV];
    {
        float p = phi_reg[0];
#pragma unroll
        for (int q = 0; q < 10; ++q) {
            acc[q*4+0] = r0[q].x*p; acc[q*4+1] = r0[q].y*p;
            acc[q*4+2] = r0[q].z*p; acc[q*4+3] = r0[q].w*p;
        }
        acc[40] = rt0.y*p; acc[41] = rt0.z*p; acc[42] = rt0.w*p;
    }
#pragma unroll
    for (int c = 1; c < 8; ++c) {
        if (c < nchunks) {
            const float* rowp = cxn + (size_t)(c*256 + t)*VV;
            f32x4u r[10];
#pragma unroll
            for (int q = 0; q < 10; ++q) r[q] = *(const f32x4u*)(rowp + q*4);
            f32x4u rt = *(const f32x4u*)(rowp + 39);
            float p = phi_reg[c];
#pragma unroll
            for (int q = 0; q < 10; ++q) {
                acc[q*4+0] += r[q].x*p; acc[q*4+1] += r[q].y*p;
                acc[q*4+2] += r[q].z*p; acc[q*4+3] += r[q].w*p;
            }
            acc[40] += rt.y*p; acc[41] += rt.z*p; acc[42] += rt.w*p;
        }
    }

#pragma unroll
    for (int v = 0; v < VV; ++v) {
        float val = acc[v];
#pragma unroll
        for (int off = 32; off > 0; off >>= 1) val += __shfl_down(val, off, 64);
        if (lane == 0) S->red[wid*VV + v] = val;
    }
    __syncthreads();
    if (t < VV) {
        float w4 = S->red[t] + S->red[VV+t] + S->red[2*VV+t] + S->red[3*VV+t];
        wt_out[n*VV + t] = w4; S->wtv[t] = w4;
    }
    __syncthreads();
    if (t < 64) {
        float v = (t == 0) ? xt[n] : (t < 44 ? S->wtv[t-1] : 0.f);
        A2[(size_t)n*64 + t] = f2bf(v);
    }
}

// ---------------------------------------------------------------------------
template<int NG, int NSA, int NSB, int EPI, int WIK, int MODE>
__global__ __launch_bounds__(256) void gemm_k(
    const ushortT* __restrict__ Ai, const float* __restrict__ Wi,
    const float* __restrict__ Ah, const float* __restrict__ Wh,
    const float* __restrict__ bih, const float* __restrict__ bhh,
    const float* __restrict__ hprev, const float* __restrict__ resv,
    float* __restrict__ outF, ushortT* __restrict__ outB,
    const float* __restrict__ Yb, float* __restrict__ preC)
{
    __shared__ __align__(16) ushortT lds0[(NG+1)*32*64];
    __shared__ __align__(16) ushortT lds1[(NG+1)*32*64];
    gemm_body<NG, NSA, NSB, EPI, WIK, MODE>(
        blockIdx.x*32, blockIdx.y*32, lds0, lds1,
        Ai, Wi, Ah, Wh, bih, bhh, hprev, resv, outF, outB, Yb, preC);
}

// ---------------------------------------------------------------------------
extern "C" void kernel_launch(void* const* d_in, const int* in_sizes, int n_in,
                              void* d_out, int out_size, void* d_ws, size_t ws_size,
                              hipStream_t stream)
{
    const float* xt   = (const float*)d_in[0];
    const float* cx   = (const float*)d_in[1];
    const float* eh   = (const float*)d_in[2];
    const float* wt_1 = (const float*)d_in[3];
    const float* h2p  = (const float*)d_in[4];
    const float* h3p  = (const float*)d_in[5];
    const float* kp   = (const float*)d_in[6];
    const float* Ww   = (const float*)d_in[7];
    const float* Wb   = (const float*)d_in[8];
    const float* w2ih = (const float*)d_in[9];
    const float* w2hh = (const float*)d_in[10];
    const float* b2ih = (const float*)d_in[11];
    const float* b2hh = (const float*)d_in[12];
    const float* w3ih = (const float*)d_in[13];
    const float* w3hh = (const float*)d_in[14];
    const float* b3ih = (const float*)d_in[15];
    const float* b3hh = (const float*)d_in[16];
    const float* Yw   = (const float*)d_in[17];
    const float* Yb   = (const float*)d_in[18];

    float* out = (float*)d_out;
    float* dist = out + OFF_DIST;
    float* h2o  = out + OFF_H2;
    float* h3o  = out + OFF_H3;
    float* phi  = out + OFF_PHI;
    float* wto  = out + OFF_WT;
    float* kapo = out + OFF_KAPPA;

    char* p = (char*)d_ws;
    ushortT* A2   = (ushortT*)p;  p += (size_t)512*64*2;
    ushortT* A3i  = (ushortT*)p;  p += (size_t)512*512*2;
    ushortT* Ad   = (ushortT*)p;  p += (size_t)512*512*2;
    float*   gh2C = (float*)p;    p += (size_t)3*PLANE*4;
    float*   gh3C = (float*)p;    p += (size_t)3*PLANE*4;

    // L1: attn + gh2 + gh3 (input-only dependencies, co-resident)
    attn_gh<<<1024, 256, 0, stream>>>(
        xt, cx, eh, wt_1, Ww, Wb, kp, phi, wto, kapo, A2,
        h2p, w2hh, h3p, w3hh, gh2C, gh3C);
    // L2: GRU2 finish: gi = A2(bf16) @ w2ih^T (K=64, 1 step) + gh2C -> h2o, A3i
    gemm_k<3, 1, 0, 1, 44, 2><<<dim3(16, 16), 256, 0, stream>>>(
        A2, w2ih, nullptr, nullptr, b2ih, b2hh, h2p, nullptr, h2o, A3i, nullptr, gh2C);
    // L3: GRU3 finish: gi = relu(h2)(bf16) @ w3ih^T (K=512) + gh3C -> h3o, Ad
    gemm_k<3, 8, 0, 2, 512, 2><<<dim3(16, 16), 256, 0, stream>>>(
        A3i, w3ih, nullptr, nullptr, b3ih, b3hh, h3p, h2o, h3o, Ad, nullptr, gh3C);
    // L4: dist = relu(h3+h2)(bf16) @ Yw^T (f32) + Yb
    gemm_k<1, 8, 0, 0, 512, 0><<<dim3(16, 16), 256, 0, stream>>>(
        Ad, Yw, nullptr, nullptr, nullptr, nullptr, nullptr, nullptr, dist, nullptr, Yb, nullptr);
}